// Round 7
// baseline (107.223 us; speedup 1.0000x reference)
//
#include <hip/hip_runtime.h>
#include <math.h>

// Chamfer distance, N=M=16384, D=3, fp32 — R9: MFMA.
// Five VALU-structured variants all plateaued at 42-46us (busy-cy/SIMD
// 60-70k, ~2x hand-count: compiler packing/marshaling overhead). MfmaUtil
// was 0.0 all along. R9 computes d^2 ENTIRELY inside one bf16 MFMA per
// 16x16 tile via K-dim split arithmetic (15 of 32 K-slots):
//   slots 0-8 : 2-way bf16 split of a and (-2b): ah*bh, ah*bl, al*bh per
//               coord (dropped al*bl ~1e-4, zero-mean)
//   slots 9-11: 3-way split of |a|^2  (x 1.0 on B side)   err ~2e-7
//   slots 12-14: 3-way split of |b|^2 (x 1.0 on A side)
// C = d^2 in fp32 to ~4e-4 abs. Both operands packed with the SAME slot
// convention, so any slot<->k permutation cancels. Fused: row-min (p1->p2)
// in 16 named reg accs, col-min (p2->p1) via 2 shfl_xor + per-wave LDS acc.
// No barriers in the j-loop. Epilogue ~1.9 VALU/output vs ~4 before.

typedef short s16x8 __attribute__((ext_vector_type(8)));
typedef float f32x4 __attribute__((ext_vector_type(4)));

constexpr int N       = 16384;
constexpr int THREADS = 256;           // 4 waves
constexpr int ISTRIP  = 256;           // i's per block (4 waves x 4 tiles x 16)
constexpr int NSTRIPS = N / ISTRIP;    // 64
constexpr int JCHUNK  = 512;           // j's per block
constexpr int NCHUNKS = N / JCHUNK;    // 32
constexpr int NJT     = JCHUNK / 16;   // 32 j-tiles per block
constexpr float INF_F = 3.402823466e+38f;
constexpr short ONE_BF = (short)0x3F80;  // bf16(1.0)

static __device__ __forceinline__ short bf_hi(float x) {  // RN bf16 bits
  unsigned u = __float_as_uint(x);
  unsigned r = (u + 0x7fffu + ((u >> 16) & 1u)) >> 16;
  return (short)r;
}
static __device__ __forceinline__ float bf_val(short h) {
  return __uint_as_float(((unsigned)(unsigned short)h) << 16);
}

__global__ __launch_bounds__(THREADS, 4) void chamfer_mfma(
    const float* __restrict__ p1, const float* __restrict__ p2,
    float* __restrict__ rowPart, float* __restrict__ colPart,
    float* __restrict__ out) {
  __shared__ s16x8 bfrag[NJT * 64];        // [jtile][lane] B operand frags, 32KB
  __shared__ float colacc[4 * JCHUNK];     // [wave][512] col-min accum, 8KB

  const int tid = threadIdx.x;
  const int l   = tid & 63;
  const int w   = tid >> 6;
  const int rr  = l & 15;    // row-in-tile (A) / col-in-tile (B,C)
  const int oct = l >> 4;    // k-octet quadrant
  const int bid = blockIdx.x;
  const int strip = bid & (NSTRIPS - 1);
  const int chunk = bid >> 6;            // NSTRIPS == 64
  const int i0 = strip * ISTRIP;
  const int j0 = chunk * JCHUNK;

  if (bid == 0 && tid == 0) *out = 0.0f;  // ordered before sum's atomics

  // ---- stage B fragments: 2 points per thread ----
  for (int jl = tid; jl < JCHUNK; jl += THREADS) {
    const float* bp = p2 + (size_t)(j0 + jl) * 3;
    const float ox = bp[0], oy = bp[1], oz = bp[2];
    const float sb = fmaf(ox, ox, fmaf(oy, oy, oz * oz));
    const float bx = -2.0f * ox, by = -2.0f * oy, bz = -2.0f * oz;
    const short bhx = bf_hi(bx), blx = bf_hi(bx - bf_val(bhx));
    const short bhy = bf_hi(by), bly = bf_hi(by - bf_val(bhy));
    const short bhz = bf_hi(bz), blz = bf_hi(bz - bf_val(bhz));
    const short sbh = bf_hi(sb);
    const float r1 = sb - bf_val(sbh);
    const short sbm = bf_hi(r1);
    const short sbl = bf_hi(r1 - bf_val(sbm));
    const int jt = jl >> 4, c = jl & 15;
    bfrag[jt * 64 + c]      = (s16x8){bhx, blx, bhx, bhy, bly, bhy, bhz, blz};
    bfrag[jt * 64 + 16 + c] = (s16x8){bhz, ONE_BF, ONE_BF, ONE_BF, sbh, sbm, sbl, 0};
    bfrag[jt * 64 + 32 + c] = (s16x8){0, 0, 0, 0, 0, 0, 0, 0};
    bfrag[jt * 64 + 48 + c] = (s16x8){0, 0, 0, 0, 0, 0, 0, 0};
  }
  for (int t = tid; t < 4 * JCHUNK; t += THREADS) colacc[t] = INF_F;

  // ---- build A fragments: 4 tiles (64 i's) per wave, in registers ----
#define ABUILD(b, AF)                                                        \
  s16x8 AF;                                                                  \
  {                                                                          \
    const float* ap = p1 + (size_t)(i0 + w * 64 + (b)*16 + rr) * 3;          \
    const float x = ap[0], y = ap[1], z = ap[2];                             \
    const float sa = fmaf(x, x, fmaf(y, y, z * z));                          \
    const short ahx = bf_hi(x), alx = bf_hi(x - bf_val(ahx));                \
    const short ahy = bf_hi(y), aly = bf_hi(y - bf_val(ahy));                \
    const short ahz = bf_hi(z), alz = bf_hi(z - bf_val(ahz));                \
    const short sah = bf_hi(sa);                                             \
    const float q1 = sa - bf_val(sah);                                       \
    const short sam = bf_hi(q1);                                             \
    const short sal = bf_hi(q1 - bf_val(sam));                               \
    if (oct == 0)                                                            \
      AF = (s16x8){ahx, ahx, alx, ahy, ahy, aly, ahz, ahz};                  \
    else if (oct == 1)                                                       \
      AF = (s16x8){alz, sah, sam, sal, ONE_BF, ONE_BF, ONE_BF, 0};           \
    else                                                                     \
      AF = (s16x8){0, 0, 0, 0, 0, 0, 0, 0};                                  \
  }
  ABUILD(0, A0) ABUILD(1, A1) ABUILD(2, A2) ABUILD(3, A3)
#undef ABUILD

  // row-min accumulators: tile b, C-reg r -> row i0 + w*64 + b*16 + oct*4 + r
  float RA00 = INF_F, RA01 = INF_F, RA02 = INF_F, RA03 = INF_F;
  float RA10 = INF_F, RA11 = INF_F, RA12 = INF_F, RA13 = INF_F;
  float RA20 = INF_F, RA21 = INF_F, RA22 = INF_F, RA23 = INF_F;
  float RA30 = INF_F, RA31 = INF_F, RA32 = INF_F, RA33 = INF_F;

  __syncthreads();

  const f32x4 zero4 = {0.0f, 0.0f, 0.0f, 0.0f};
  float* const cabase = &colacc[w * JCHUNK + rr];
  for (int jt = 0; jt < NJT; ++jt) {
    const s16x8 bf = bfrag[jt * 64 + l];  // ds_read_b128, conflict-free
    const f32x4 C0 = __builtin_amdgcn_mfma_f32_16x16x32_bf16(A0, bf, zero4, 0, 0, 0);
    const f32x4 C1 = __builtin_amdgcn_mfma_f32_16x16x32_bf16(A1, bf, zero4, 0, 0, 0);
    const f32x4 C2 = __builtin_amdgcn_mfma_f32_16x16x32_bf16(A2, bf, zero4, 0, 0, 0);
    const f32x4 C3 = __builtin_amdgcn_mfma_f32_16x16x32_bf16(A3, bf, zero4, 0, 0, 0);
    // row-min: each C reg is one row (i), this lane's col (j)
    RA00 = fminf(RA00, C0[0]); RA01 = fminf(RA01, C0[1]);
    RA02 = fminf(RA02, C0[2]); RA03 = fminf(RA03, C0[3]);
    RA10 = fminf(RA10, C1[0]); RA11 = fminf(RA11, C1[1]);
    RA12 = fminf(RA12, C1[2]); RA13 = fminf(RA13, C1[3]);
    RA20 = fminf(RA20, C2[0]); RA21 = fminf(RA21, C2[1]);
    RA22 = fminf(RA22, C2[2]); RA23 = fminf(RA23, C2[3]);
    RA30 = fminf(RA30, C3[0]); RA31 = fminf(RA31, C3[1]);
    RA32 = fminf(RA32, C3[2]); RA33 = fminf(RA33, C3[3]);
    // col-min: min over this lane's 16 rows, then across the 4 quadrants
    const float t0 = fminf(fminf(C0[0], C0[1]), fminf(C0[2], C0[3]));
    const float t1 = fminf(fminf(C1[0], C1[1]), fminf(C1[2], C1[3]));
    const float t2 = fminf(fminf(C2[0], C2[1]), fminf(C2[2], C2[3]));
    const float t3 = fminf(fminf(C3[0], C3[1]), fminf(C3[2], C3[3]));
    float cm = fminf(fminf(t0, t1), fminf(t2, t3));
    cm = fminf(cm, __shfl_xor(cm, 16, 64));
    cm = fminf(cm, __shfl_xor(cm, 32, 64));
    if (oct == 0) {  // one lane per col; per-wave region -> no races
      float* ca = cabase + jt * 16;
      *ca = fminf(*ca, cm);
    }
  }

  // ---- row-min finish: reduce the 16 lanes sharing (oct, reg) ----
#define RFIN(b, r, RA)                                                       \
  RA = fminf(RA, __shfl_xor(RA, 1, 64));                                     \
  RA = fminf(RA, __shfl_xor(RA, 2, 64));                                     \
  RA = fminf(RA, __shfl_xor(RA, 4, 64));                                     \
  RA = fminf(RA, __shfl_xor(RA, 8, 64));                                     \
  if (rr == 0)                                                               \
    rowPart[(size_t)chunk * N + i0 + w * 64 + (b)*16 + oct * 4 + (r)] = RA;
  RFIN(0, 0, RA00) RFIN(0, 1, RA01) RFIN(0, 2, RA02) RFIN(0, 3, RA03)
  RFIN(1, 0, RA10) RFIN(1, 1, RA11) RFIN(1, 2, RA12) RFIN(1, 3, RA13)
  RFIN(2, 0, RA20) RFIN(2, 1, RA21) RFIN(2, 2, RA22) RFIN(2, 3, RA23)
  RFIN(3, 0, RA30) RFIN(3, 1, RA31) RFIN(3, 2, RA32) RFIN(3, 3, RA33)
#undef RFIN

  // ---- col-min finish: merge the 4 waves ----
  __syncthreads();
  for (int c = tid; c < JCHUNK; c += THREADS) {
    const float m = fminf(fminf(colacc[c], colacc[JCHUNK + c]),
                          fminf(colacc[2 * JCHUNK + c], colacc[3 * JCHUNK + c]));
    colPart[(size_t)strip * N + j0 + c] = m;
  }
}

// One thread per point (2*16384): min over partials (d^2 already complete —
// norms were inside the MFMA), sqrt, block-sum, one atomicAdd into out[0].
__global__ __launch_bounds__(THREADS) void chamfer_sum(
    const float* __restrict__ rowPart, const float* __restrict__ colPart,
    float* __restrict__ out) {
  const int p = blockIdx.x * THREADS + threadIdx.x;  // 0..32767
  float m0 = INF_F, m1 = INF_F, m2 = INF_F, m3 = INF_F;
  if (p < N) {
    const float* rp = rowPart + p;
    for (int c = 0; c < NCHUNKS; c += 4) {
      m0 = fminf(m0, rp[(size_t)(c + 0) * N]);
      m1 = fminf(m1, rp[(size_t)(c + 1) * N]);
      m2 = fminf(m2, rp[(size_t)(c + 2) * N]);
      m3 = fminf(m3, rp[(size_t)(c + 3) * N]);
    }
  } else {
    const float* cp = colPart + (p - N);
    for (int s = 0; s < NSTRIPS; s += 4) {
      m0 = fminf(m0, cp[(size_t)(s + 0) * N]);
      m1 = fminf(m1, cp[(size_t)(s + 1) * N]);
      m2 = fminf(m2, cp[(size_t)(s + 2) * N]);
      m3 = fminf(m3, cp[(size_t)(s + 3) * N]);
    }
  }
  float d = sqrtf(fmaxf(fminf(fminf(m0, m1), fminf(m2, m3)), 0.0f));

  for (int off = 32; off > 0; off >>= 1) d += __shfl_down(d, off, 64);
  __shared__ float red[THREADS / 64];
  const int wave = threadIdx.x >> 6;
  const int lane = threadIdx.x & 63;
  if (lane == 0) red[wave] = d;
  __syncthreads();
  if (threadIdx.x == 0) {
    float s = 0.0f;
    for (int wv = 0; wv < THREADS / 64; ++wv) s += red[wv];
    atomicAdd(out, s);
  }
}

extern "C" void kernel_launch(void* const* d_in, const int* in_sizes, int n_in,
                              void* d_out, int out_size, void* d_ws, size_t ws_size,
                              hipStream_t stream) {
  const float* p1 = (const float*)d_in[0];
  const float* p2 = (const float*)d_in[1];
  float* out = (float*)d_out;
  float* ws = (float*)d_ws;

  // ws: rowPart[NCHUNKS=32][N] (2MB) + colPart[NSTRIPS=64][N] (4MB).
  // Prior rounds proved ws >= 8MB.
  float* rowPart = ws;
  float* colPart = ws + (size_t)NCHUNKS * N;

  chamfer_mfma<<<dim3(NSTRIPS * NCHUNKS), THREADS, 0, stream>>>(
      p1, p2, rowPart, colPart, out);
  chamfer_sum<<<dim3((2 * N) / THREADS), THREADS, 0, stream>>>(rowPart, colPart,
                                                               out);
}

// Round 8
// 95.240 us; speedup vs baseline: 1.1258x; 1.1258x over previous
//
#include <hip/hip_runtime.h>
#include <math.h>

// Chamfer distance, N=M=16384, D=3, fp32 — R10: 32x32x16 MFMA, lean epilogue.
// R9 (16x16x32) passed bit-clean but spent 86k busy-cy/SIMD on epilogue:
// per-iter shfl_xor pair + exec-masked LDS rmw + 4 fragmented C's, and 17/32
// K-slots were zero. R10 uses mfma_f32_32x32x16_bf16: K=16 fits the 15-slot
// split arithmetic with 1 wasted slot, and ALL 16 C regs of a lane share one
// column (col=lane&31) =>
//   row-min: 2x elementwise_min on f32x16 (no extraction),
//   col-min: elementwise_min + in-vector tree -> 1 value -> 1 unmasked LDS
//            rmw at a per-(wave,half)-exclusive row. No shuffles, no exec
//            masks, no barriers inside the j-loop.
// Slot convention (identical on both operands => any k-permutation cancels):
//   k0-8: 2-way bf16 split cross terms (ah*bh, ah*bl, al*bh per coord)
//   k9-11: 3-way split |a|^2 (x1 on B)   k12-14: 3-way split |b|^2 (x1 on A)

typedef short s16x8 __attribute__((ext_vector_type(8)));
typedef float f32x16 __attribute__((ext_vector_type(16)));

constexpr int N       = 16384;
constexpr int THREADS = 256;           // 4 waves
constexpr int ISTRIP  = 256;           // i's per block (4 waves x 2 tiles x 32)
constexpr int NSTRIPS = N / ISTRIP;    // 64
constexpr int JCHUNK  = 512;           // j's per block
constexpr int NCHUNKS = N / JCHUNK;    // 32
constexpr int NJT     = JCHUNK / 32;   // 16 j-tiles per block
constexpr int CPAD    = 528;           // colacc row stride (512+16)
constexpr float INF_F = 3.402823466e+38f;
constexpr short ONE_BF = (short)0x3F80;  // bf16(1.0)

static __device__ __forceinline__ short bf_hi(float x) {  // RN bf16 bits
  unsigned u = __float_as_uint(x);
  unsigned r = (u + 0x7fffu + ((u >> 16) & 1u)) >> 16;
  return (short)r;
}
static __device__ __forceinline__ float bf_val(short h) {
  return __uint_as_float(((unsigned)(unsigned short)h) << 16);
}

__global__ __launch_bounds__(THREADS, 4) void chamfer_mfma(
    const float* __restrict__ p1, const float* __restrict__ p2,
    float* __restrict__ rowPart, float* __restrict__ colPart,
    float* __restrict__ out) {
  __shared__ s16x8 bfrag[NJT * 64];     // [jtile][lane] B frags, 16 KB
  __shared__ float colacc[8 * CPAD];    // [wave*2+half][512+pad], 16.5 KB

  const int tid  = threadIdx.x;
  const int l    = tid & 63;
  const int w    = tid >> 6;
  const int cl   = l & 31;   // col-in-tile (B,C) / row-in-tile (A)
  const int half = l >> 5;   // k-half owner
  const int bid  = blockIdx.x;
  const int strip = bid & (NSTRIPS - 1);
  const int chunk = bid >> 6;            // NSTRIPS == 64
  const int i0 = strip * ISTRIP;
  const int j0 = chunk * JCHUNK;

  if (bid == 0 && tid == 0) *out = 0.0f;  // ordered before sum's atomics

  // ---- stage B fragments: 2 points per thread ----
  for (int jl = tid; jl < JCHUNK; jl += THREADS) {
    const float* bp = p2 + (size_t)(j0 + jl) * 3;
    const float ox = bp[0], oy = bp[1], oz = bp[2];
    const float sb = fmaf(ox, ox, fmaf(oy, oy, oz * oz));
    const float bx = -2.0f * ox, by = -2.0f * oy, bz = -2.0f * oz;
    const short bhx = bf_hi(bx), blx = bf_hi(bx - bf_val(bhx));
    const short bhy = bf_hi(by), bly = bf_hi(by - bf_val(bhy));
    const short bhz = bf_hi(bz), blz = bf_hi(bz - bf_val(bhz));
    const short sbh = bf_hi(sb);
    const float r1 = sb - bf_val(sbh);
    const short sbm = bf_hi(r1);
    const short sbl = bf_hi(r1 - bf_val(sbm));
    const int jt = jl >> 5, c = jl & 31;
    bfrag[jt * 64 + c]      = (s16x8){bhx, blx, bhx, bhy, bly, bhy, bhz, blz};
    bfrag[jt * 64 + 32 + c] = (s16x8){bhz, ONE_BF, ONE_BF, ONE_BF,
                                      sbh, sbm, sbl, 0};
  }
  for (int t = tid; t < 8 * CPAD; t += THREADS) colacc[t] = INF_F;

  // ---- A fragments: 2 row-tiles (64 i's) per wave, in registers ----
#define ABUILD(t, AF)                                                        \
  s16x8 AF;                                                                  \
  {                                                                          \
    const float* ap = p1 + (size_t)(i0 + w * 64 + (t)*32 + cl) * 3;          \
    const float x = ap[0], y = ap[1], z = ap[2];                             \
    const float sa = fmaf(x, x, fmaf(y, y, z * z));                          \
    const short ahx = bf_hi(x), alx = bf_hi(x - bf_val(ahx));                \
    const short ahy = bf_hi(y), aly = bf_hi(y - bf_val(ahy));                \
    const short ahz = bf_hi(z), alz = bf_hi(z - bf_val(ahz));                \
    const short sah = bf_hi(sa);                                             \
    const float q1 = sa - bf_val(sah);                                       \
    const short sam = bf_hi(q1);                                             \
    const short sal = bf_hi(q1 - bf_val(sam));                               \
    AF = half ? (s16x8){alz, sah, sam, sal, ONE_BF, ONE_BF, ONE_BF, 0}       \
              : (s16x8){ahx, ahx, alx, ahy, ahy, aly, ahz, ahz};             \
  }
  ABUILD(0, A0) ABUILD(1, A1)
#undef ABUILD

  f32x16 RAa, RAb;
#pragma unroll
  for (int r = 0; r < 16; ++r) { RAa[r] = INF_F; RAb[r] = INF_F; }
  const f32x16 zero16 = RAa - RAa;  // {0,...}

  float* const cab = &colacc[((w << 1) | half) * CPAD + cl];

  __syncthreads();

#pragma unroll 2
  for (int jt = 0; jt < NJT; ++jt) {
    const s16x8 bf = bfrag[jt * 64 + l];  // contiguous ds_read_b128
    const f32x16 C0 =
        __builtin_amdgcn_mfma_f32_32x32x16_bf16(A0, bf, zero16, 0, 0, 0);
    const f32x16 C1 =
        __builtin_amdgcn_mfma_f32_32x32x16_bf16(A1, bf, zero16, 0, 0, 0);
    // row-min: vector accumulate, no extraction
    RAa = __builtin_elementwise_min(RAa, C0);
    RAb = __builtin_elementwise_min(RAb, C1);
    // col-min: this lane's 32 C values all share column cl
    const f32x16 t = __builtin_elementwise_min(C0, C1);
    const float u0 = fminf(fminf(t[0], t[1]), fminf(t[2], t[3]));
    const float u1 = fminf(fminf(t[4], t[5]), fminf(t[6], t[7]));
    const float u2 = fminf(fminf(t[8], t[9]), fminf(t[10], t[11]));
    const float u3 = fminf(fminf(t[12], t[13]), fminf(t[14], t[15]));
    const float cm = fminf(fminf(u0, u1), fminf(u2, u3));
    float* ca = cab + (jt << 5);  // exclusive (wave,half) row: plain rmw
    *ca = fminf(*ca, cm);
  }

  // ---- row-min finish: butterfly over the 32 col-lanes of each half ----
#define RFIN(RV, t)                                                          \
  _Pragma("unroll") for (int r = 0; r < 16; ++r) {                           \
    float v = RV[r];                                                         \
    v = fminf(v, __shfl_xor(v, 1, 64));                                      \
    v = fminf(v, __shfl_xor(v, 2, 64));                                      \
    v = fminf(v, __shfl_xor(v, 4, 64));                                      \
    v = fminf(v, __shfl_xor(v, 8, 64));                                      \
    v = fminf(v, __shfl_xor(v, 16, 64));                                     \
    if (cl == 0) {                                                           \
      const int row = (r & 3) + 8 * (r >> 2) + 4 * half;                     \
      rowPart[(size_t)chunk * N + i0 + w * 64 + (t)*32 + row] = v;           \
    }                                                                        \
  }
  RFIN(RAa, 0) RFIN(RAb, 1)
#undef RFIN

  // ---- col-min finish: merge the 8 (wave,half) rows ----
  __syncthreads();
  for (int c = tid; c < JCHUNK; c += THREADS) {
    float m = colacc[c];
#pragma unroll
    for (int r = 1; r < 8; ++r) m = fminf(m, colacc[r * CPAD + c]);
    colPart[(size_t)strip * N + j0 + c] = m;
  }
}

// One thread per point (2*16384): min over partials (d^2 already complete —
// norms were inside the MFMA), sqrt, block-sum, one atomicAdd into out[0].
__global__ __launch_bounds__(THREADS) void chamfer_sum(
    const float* __restrict__ rowPart, const float* __restrict__ colPart,
    float* __restrict__ out) {
  const int p = blockIdx.x * THREADS + threadIdx.x;  // 0..32767
  float m0 = INF_F, m1 = INF_F, m2 = INF_F, m3 = INF_F;
  if (p < N) {
    const float* rp = rowPart + p;
    for (int c = 0; c < NCHUNKS; c += 4) {
      m0 = fminf(m0, rp[(size_t)(c + 0) * N]);
      m1 = fminf(m1, rp[(size_t)(c + 1) * N]);
      m2 = fminf(m2, rp[(size_t)(c + 2) * N]);
      m3 = fminf(m3, rp[(size_t)(c + 3) * N]);
    }
  } else {
    const float* cp = colPart + (p - N);
    for (int s = 0; s < NSTRIPS; s += 4) {
      m0 = fminf(m0, cp[(size_t)(s + 0) * N]);
      m1 = fminf(m1, cp[(size_t)(s + 1) * N]);
      m2 = fminf(m2, cp[(size_t)(s + 2) * N]);
      m3 = fminf(m3, cp[(size_t)(s + 3) * N]);
    }
  }
  float d = sqrtf(fmaxf(fminf(fminf(m0, m1), fminf(m2, m3)), 0.0f));

  for (int off = 32; off > 0; off >>= 1) d += __shfl_down(d, off, 64);
  __shared__ float red[THREADS / 64];
  const int wave = threadIdx.x >> 6;
  const int lane = threadIdx.x & 63;
  if (lane == 0) red[wave] = d;
  __syncthreads();
  if (threadIdx.x == 0) {
    float s = 0.0f;
    for (int wv = 0; wv < THREADS / 64; ++wv) s += red[wv];
    atomicAdd(out, s);
  }
}

extern "C" void kernel_launch(void* const* d_in, const int* in_sizes, int n_in,
                              void* d_out, int out_size, void* d_ws, size_t ws_size,
                              hipStream_t stream) {
  const float* p1 = (const float*)d_in[0];
  const float* p2 = (const float*)d_in[1];
  float* out = (float*)d_out;
  float* ws = (float*)d_ws;

  // ws: rowPart[NCHUNKS=32][N] (2MB) + colPart[NSTRIPS=64][N] (4MB).
  float* rowPart = ws;
  float* colPart = ws + (size_t)NCHUNKS * N;

  chamfer_mfma<<<dim3(NSTRIPS * NCHUNKS), THREADS, 0, stream>>>(
      p1, p2, rowPart, colPart, out);
  chamfer_sum<<<dim3((2 * N) / THREADS), THREADS, 0, stream>>>(rowPart, colPart,
                                                               out);
}